// Round 5
// baseline (353.134 us; speedup 1.0000x reference)
//
#include <hip/hip_runtime.h>
#include <stdint.h>

#define SEQ 2048
// B=2, DIM=2048, NH=16, NKV=4, HD=128, qkv width = 2048+512+512 = 3072

typedef uint16_t u16;
typedef uint32_t u32;
typedef __attribute__((ext_vector_type(4))) float f32x4;
typedef __attribute__((ext_vector_type(8))) __bf16 bf16x8;
typedef __attribute__((ext_vector_type(4))) __bf16 bf16x4;

__device__ __forceinline__ u16 f2bf(float f) {
    u32 u = __float_as_uint(f);
    u += 0x7FFFu + ((u >> 16) & 1u);   // RNE
    return (u16)(u >> 16);
}
__device__ __forceinline__ float bf2f(u16 h) {
    return __uint_as_float(((u32)h) << 16);
}
__device__ __forceinline__ void async16(const void* g, void* l) {
    auto gp = (__attribute__((address_space(1))) void*)const_cast<void*>(g);
    auto lp = (__attribute__((address_space(3))) void*)l;
    __builtin_amdgcn_global_load_lds(gp, lp, 16, 0, 0);
}

#define QSCALE (0.088388347762f * 1.4426950408889634f)   // (1/sqrt(128))*log2(e)

// ---------------- fp32 -> bf16 elementwise (x) ----------------
__global__ __launch_bounds__(256) void convert_bf16(const float* __restrict__ src,
                                                    u16* __restrict__ dst) {
    int i = blockIdx.x * 256 + threadIdx.x;      // one float4 per thread
    float4 v = ((const float4*)src)[i];
    u32 lo = (u32)f2bf(v.x) | ((u32)f2bf(v.y) << 16);
    u32 hi = (u32)f2bf(v.z) | ((u32)f2bf(v.w) << 16);
    ((uint2*)dst)[i] = make_uint2(lo, hi);
}

// ------------- all 4 weights: fp32 [K][N] -> bf16 transposed [N][K], one launch -------------
// grid (80, 32): nt<32 wq | nt<40 wk | nt<48 wv | else wo.  dst row stride = 2048.
__global__ __launch_bounds__(256) void tconv_all(const float* __restrict__ wq,
                                                 const float* __restrict__ wk,
                                                 const float* __restrict__ wv,
                                                 const float* __restrict__ wo,
                                                 u16* __restrict__ wqkvT,
                                                 u16* __restrict__ woT) {
    __shared__ float tile[64][65];
    const int nt = blockIdx.x, kt = blockIdx.y;
    const float* src; u16* dst; int N, nloc;
    if (nt < 32)      { src = wq; dst = wqkvT;                        N = 2048; nloc = nt; }
    else if (nt < 40) { src = wk; dst = wqkvT + (size_t)2048 * 2048;  N = 512;  nloc = nt - 32; }
    else if (nt < 48) { src = wv; dst = wqkvT + (size_t)2560 * 2048;  N = 512;  nloc = nt - 40; }
    else              { src = wo; dst = woT;                          N = 2048; nloc = nt - 48; }
    const int n0 = nloc * 64, k0 = kt * 64;
    const int tid = threadIdx.x;
#pragma unroll
    for (int p = 0; p < 4; p++) {
        int r = p * 16 + (tid >> 4);
        int c = (tid & 15) * 4;
        float4 v = *(const float4*)&src[(size_t)(k0 + r) * N + n0 + c];
        tile[r][c] = v.x; tile[r][c+1] = v.y; tile[r][c+2] = v.z; tile[r][c+3] = v.w;
    }
    __syncthreads();
#pragma unroll
    for (int p = 0; p < 4; p++) {
        int n = p * 16 + (tid >> 4);
        int kq = (tid & 15) * 4;
        u32 lo = (u32)f2bf(tile[kq+0][n]) | ((u32)f2bf(tile[kq+1][n]) << 16);
        u32 hi = (u32)f2bf(tile[kq+2][n]) | ((u32)f2bf(tile[kq+3][n]) << 16);
        *(uint2*)&dst[(size_t)(n0 + n) * 2048 + k0 + kq] = make_uint2(lo, hi);
    }
}

// ---------------- bf16 GEMM: C[M,N] = A[M,K] * Bt[N,K]^T ----------------
// MODE 1: plain fp32 store (out-proj).
// MODE 2: QKV fused epilogue — Q cols: RoPE*qscale -> qkvb; K cols: RoPE -> qkvb;
//         V cols: transpose via per-wave LDS -> vt[(b*4+kh)*128+d][s].
template <int MODE>
__global__ __launch_bounds__(256) void gemm128(const u16* __restrict__ A,
                                               const u16* __restrict__ Bt,
                                               void* __restrict__ Cv,
                                               u16* __restrict__ vt,
                                               const float* __restrict__ cosp,
                                               const float* __restrict__ sinp,
                                               int M, int N, int K) {
    __shared__ u16 sh[(MODE == 2) ? 16384 : 8192];
    u16* lA = sh;
    u16* lB = sh + 4096;
    const int tid = threadIdx.x;
    const int m0 = blockIdx.y * 128, n0 = blockIdx.x * 128;
    const int lane = tid & 63;
    const int lr = lane & 15, quad = lane >> 4;
    const int w = tid >> 6;
    const int wm = (w >> 1) * 64, wn = (w & 1) * 64;

    f32x4 acc[4][4] = {};

    const int srow = tid >> 2;
    const int schunk = (tid & 3) ^ (srow & 3);
    const u16* aS0 = A  + (size_t)(m0 + srow) * K + schunk * 8;
    const u16* aS1 = aS0 + (size_t)64 * K;
    const u16* bS0 = Bt + (size_t)(n0 + srow) * K + schunk * 8;
    const u16* bS1 = bS0 + (size_t)64 * K;
    u16* lAd = lA + tid * 8;
    u16* lBd = lB + tid * 8;

    for (int k0 = 0; k0 < K; k0 += 32) {
        __syncthreads();
        async16(aS0 + k0, lAd);
        async16(aS1 + k0, lAd + 2048);
        async16(bS0 + k0, lBd);
        async16(bS1 + k0, lBd + 2048);
        __syncthreads();
        bf16x8 af[4], bfr[4];
        const int cs = (quad ^ (lr & 3)) * 8;
#pragma unroll
        for (int i = 0; i < 4; i++)
            af[i] = *(const bf16x8*)&lA[(wm + i * 16 + lr) * 32 + cs];
#pragma unroll
        for (int i = 0; i < 4; i++)
            bfr[i] = *(const bf16x8*)&lB[(wn + i * 16 + lr) * 32 + cs];
#pragma unroll
        for (int mf = 0; mf < 4; mf++)
#pragma unroll
            for (int nf = 0; nf < 4; nf++)
                acc[mf][nf] = __builtin_amdgcn_mfma_f32_16x16x32_bf16(
                    af[mf], bfr[nf], acc[mf][nf], 0, 0, 0);
    }

    if (MODE == 1) {
#pragma unroll
        for (int mf = 0; mf < 4; mf++)
#pragma unroll
            for (int nf = 0; nf < 4; nf++)
#pragma unroll
                for (int r = 0; r < 4; r++) {
                    size_t row = (size_t)(m0 + wm + mf * 16 + quad * 4 + r);
                    size_t col = (size_t)(n0 + wn + nf * 16 + lr);
                    ((float*)Cv)[row * (size_t)N + col] = acc[mf][nf][r];
                }
    } else {
        const int ncol0 = n0 + wn;                 // region is block-uniform (128-aligned bounds)
        if (ncol0 < 2560) {
            // Q or K: RoPE (pairs = adjacent lanes), Q additionally scaled
            const float s2 = (ncol0 < 2048) ? QSCALE : 1.0f;
#pragma unroll
            for (int mf = 0; mf < 4; mf++) {
                const int tokb = m0 + wm + mf * 16 + quad * 4;
#pragma unroll
                for (int nf = 0; nf < 4; nf++) {
                    const int ci = (((ncol0 & 127) + nf * 16 + lr) >> 1);
#pragma unroll
                    for (int r = 0; r < 4; r++) {
                        int tok = tokb + r;
                        int spos = tok & (SEQ - 1);
                        float cv = cosp[spos * 64 + ci] * s2;
                        float sv = sinp[spos * 64 + ci] * s2;
                        float val = acc[mf][nf][r];
                        float par = __shfl_xor(val, 1);
                        float outv = (lane & 1) ? fmaf(par, sv, val * cv)
                                                : fmaf(val, cv, -par * sv);
                        ((u16*)Cv)[(size_t)tok * 3072 + ncol0 + nf * 16 + lr] = f2bf(outv);
                    }
                }
            }
        } else {
            // V: per-wave 64x64 transpose via LDS (rotation swizzle), store to vt
            __syncthreads();                       // lA/lB dead for ALL waves
            u16* tr = sh + w * 4096;               // 8 KB per wave
#pragma unroll
            for (int mf = 0; mf < 4; mf++)
#pragma unroll
                for (int nf = 0; nf < 4; nf++)
#pragma unroll
                    for (int r = 0; r < 4; r++) {
                        int row  = mf * 16 + quad * 4 + r;     // token local
                        int colL = nf * 16 + lr;               // d local
                        tr[colL * 64 + ((row + 8 * colL) & 63)] = f2bf(acc[mf][nf][r]);
                    }
            // same-wave read-back (ds ordering; no barrier needed)
            const int b = m0 >> 11;
            const int s0base = (m0 & 2047) + wm;
#pragma unroll
            for (int i = 0; i < 8; i++) {
                int dL = i * 8 + (lane >> 3);
                int t0 = (lane & 7) * 8;
                uint4 v = *(const uint4*)&tr[dL * 64 + ((t0 + 8 * dL) & 63)];
                int dglob = (ncol0 - 2560) + dL;
                int khh = dglob >> 7, dh = dglob & 127;
                *(uint4*)&vt[((size_t)((b * 4 + khh) * 128 + dh)) * SEQ + s0base + t0] = v;
            }
        }
    }
}

// ---------------- causal GQA flash attention: uniform K-split + K-double-buffer ----------------
// grid = 256, 512 threads = 2 groups x 4 waves; every group does exactly 17 iters.
// K double-buffered (prefetch t+1), V single-buffered; fine vmcnt(8)/(4), 3 raw barriers/iter.
// Q read pre-roped & pre-scaled from qkvb. LDS = 128 KB (1 block/CU).
__global__ __launch_bounds__(512, 1) void flash_attn(const u16* __restrict__ qkv,
                                                     const u16* __restrict__ vt,
                                                     u16* __restrict__ ob) {
    __shared__ u16 sh[65536];                    // 128 KB
    const int bidx = blockIdx.x;
    const int a  = bidx & 7;
    const int bh = bidx >> 3;
    const int b = bh >> 4, h = bh & 15, kh = h >> 2;
    const int tid = threadIdx.x;
    const int w = tid >> 6, lane = tid & 63;
    const int grp = w >> 2, wl = w & 3;
    const int lr = lane & 15, quad = lane >> 4;

    u16* kb0 = sh + grp * 24576;                 // K buf0 (64x128)
    u16* kb1 = kb0 + 8192;                       // K buf1
    u16* lVg = kb0 + 16384;                      // V (128x64)
    u16* lPw = sh + 49152 + w * 2048;            // P per wave (32x64)

    const int tidg = tid & 255;
    const int krow = tidg >> 4;
    const int kchunk = (tidg & 15) ^ krow;
    const int vrow = tidg >> 3;
    const int vchunk = (tidg & 7) ^ (vrow & 7);
    const u16* kRow = qkv + (size_t)b * SEQ * 3072 + 2048 + kh * 128
                    + (size_t)krow * 3072 + kchunk * 8;
    const u16* vRow = vt + (size_t)(b * 4 + kh) * 128 * SEQ
                    + (size_t)vrow * SEQ + vchunk * 8;
    u16* lVd = lVg + tidg * 8;

    float* mO = (float*)sh;                      // merge scratch: 128 x 132 f32 (padded)
    float* mM = (float*)(sh + 49152);            // merge scratch: 128 x (m,l)

    for (int p = 0; p < 2; p++) {
        const int qt = p ? (7 - a) : (8 + a);
        const int niters = p ? (8 - a) : (9 + a);
        const int kt0 = grp * niters;

        // Q fragments (A-layout), pre-roped & pre-scaled by GEMM epilogue
        bf16x8 qf[2][4];
#pragma unroll
        for (int qi = 0; qi < 2; qi++) {
            const u16* qb = qkv + (size_t)(b * SEQ + qt * 128 + wl * 32 + qi * 16 + lr) * 3072 + h * 128;
#pragma unroll
            for (int kk = 0; kk < 4; kk++)
                qf[qi][kk] = *(const bf16x8*)(qb + kk * 32 + quad * 8);
        }

        f32x4 o[2][8] = {};
        float m_st[2] = {-1e30f, -1e30f};
        float l_st[2] = {0.f, 0.f};
        const int qg = qt * 128 + wl * 32 + lr;

        // prologue: K(kt0) -> kb0
        {
            u16* d = kb0 + tidg * 8;
#pragma unroll
            for (int i = 0; i < 4; i++)
                async16(kRow + (size_t)(kt0 * 64 + i * 16) * 3072, d + i * 2048);
        }

        for (int t = 0; t < niters; t++) {
            const int kt = kt0 + t;
            // V(t)
#pragma unroll
            for (int i = 0; i < 4; i++)
                async16(vRow + (size_t)(i * 32) * SEQ + kt * 64, lVd + i * 2048);
            // K(t+1) prefetch into alternate buffer
            if (t + 1 < niters) {
                u16* d = ((t + 1) & 1 ? kb1 : kb0) + tidg * 8;
#pragma unroll
                for (int i = 0; i < 4; i++)
                    async16(kRow + (size_t)((kt + 1) * 64 + i * 16) * 3072, d + i * 2048);
                asm volatile("s_waitcnt vmcnt(8)" ::: "memory");   // K(t) drained
            } else {
                asm volatile("s_waitcnt vmcnt(4)" ::: "memory");   // K(t) drained
            }
            asm volatile("s_barrier" ::: "memory");

            const u16* lKc = (t & 1) ? kb1 : kb0;

            // S^T = K Q^T : C cols = q (lane&15), rows = key (quad*4+r)
            f32x4 sc[2][4] = {};
#pragma unroll
            for (int nf = 0; nf < 4; nf++) {
#pragma unroll
                for (int kk = 0; kk < 4; kk++) {
                    bf16x8 ak = *(const bf16x8*)&lKc[(nf * 16 + lr) * 128 + (((kk * 4 + quad) ^ lr) * 8)];
                    sc[0][nf] = __builtin_amdgcn_mfma_f32_16x16x32_bf16(ak, qf[0][kk], sc[0][nf], 0, 0, 0);
                    sc[1][nf] = __builtin_amdgcn_mfma_f32_16x16x32_bf16(ak, qf[1][kk], sc[1][nf], 0, 0, 0);
                }
            }

            const int kb_ = kt * 64 + quad * 4;
#pragma unroll
            for (int qi = 0; qi < 2; qi++) {
                float ps[4][4];
                float mnew = m_st[qi];
                const int qrow_g = qg + qi * 16;
#pragma unroll
                for (int nf = 0; nf < 4; nf++)
#pragma unroll
                    for (int r = 0; r < 4; r++) {
                        float v = sc[qi][nf][r];
                        if ((kb_ + nf * 16 + r) > qrow_g) v = -1e30f;
                        ps[nf][r] = v;
                        mnew = fmaxf(mnew, v);
                    }
                mnew = fmaxf(mnew, __shfl_xor(mnew, 16));
                mnew = fmaxf(mnew, __shfl_xor(mnew, 32));
                float rsum = 0.f;
#pragma unroll
                for (int nf = 0; nf < 4; nf++)
#pragma unroll
                    for (int r = 0; r < 4; r++) {
                        float e = exp2f(ps[nf][r] - mnew);
                        ps[nf][r] = e;
                        rsum += e;
                    }
                rsum += __shfl_xor(rsum, 16);
                rsum += __shfl_xor(rsum, 32);
                float alpha = exp2f(m_st[qi] - mnew);
                l_st[qi] = l_st[qi] * alpha + rsum;
                m_st[qi] = mnew;
#pragma unroll
                for (int r = 0; r < 4; r++) {
                    float ar = __shfl(alpha, quad * 4 + r, 16);
#pragma unroll
                    for (int nd = 0; nd < 8; nd++) o[qi][nd][r] *= ar;
                }
                const int qrow = qi * 16 + lr;
#pragma unroll
                for (int nf = 0; nf < 4; nf++) {
                    u32 lo = (u32)f2bf(ps[nf][0]) | ((u32)f2bf(ps[nf][1]) << 16);
                    u32 hi = (u32)f2bf(ps[nf][2]) | ((u32)f2bf(ps[nf][3]) << 16);
                    int c = (nf * 4 + quad) ^ lr;
                    *(uint2*)&lPw[qrow * 64 + c * 4] = make_uint2(lo, hi);
                }
            }

            // V(t) visible to whole group, then PV
            if (t + 1 < niters) asm volatile("s_waitcnt vmcnt(4)" ::: "memory");
            else                asm volatile("s_waitcnt vmcnt(0)" ::: "memory");
            asm volatile("s_barrier" ::: "memory");

#pragma unroll
            for (int kf = 0; kf < 2; kf++) {
                bf16x8 pa[2];
#pragma unroll
                for (int qi = 0; qi < 2; qi++) {
                    int c0 = (kf * 8 + quad * 2) ^ lr;
                    int c1 = (kf * 8 + quad * 2 + 1) ^ lr;
                    bf16x4 p0 = *(const bf16x4*)&lPw[(qi * 16 + lr) * 64 + c0 * 4];
                    bf16x4 p1 = *(const bf16x4*)&lPw[(qi * 16 + lr) * 64 + c1 * 4];
                    pa[qi] = __builtin_shufflevector(p0, p1, 0, 1, 2, 3, 4, 5, 6, 7);
                }
#pragma unroll
                for (int nd = 0; nd < 8; nd++) {
                    bf16x8 vb = *(const bf16x8*)&lVg[(nd * 16 + lr) * 64 + (((kf * 4 + quad) ^ (lr & 7)) * 8)];
                    o[0][nd] = __builtin_amdgcn_mfma_f32_16x16x32_bf16(pa[0], vb, o[0][nd], 0, 0, 0);
                    o[1][nd] = __builtin_amdgcn_mfma_f32_16x16x32_bf16(pa[1], vb, o[1][nd], 0, 0, 0);
                }
            }

            asm volatile("s_barrier" ::: "memory");   // V reads done -> next iter may restage
        }

        // ---- in-block merge of the two K-halves (mO padded stride 132) ----
        __syncthreads();
        if (grp == 1) {
#pragma unroll
            for (int qi = 0; qi < 2; qi++) {
#pragma unroll
                for (int r = 0; r < 4; r++) {
                    int row = wl * 32 + qi * 16 + quad * 4 + r;
#pragma unroll
                    for (int nd = 0; nd < 8; nd++)
                        mO[row * 132 + nd * 16 + lr] = o[qi][nd][r];
                }
                if (quad == 0) {
                    int rowl = wl * 32 + qi * 16 + lr;
                    mM[rowl * 2]     = m_st[qi];
                    mM[rowl * 2 + 1] = l_st[qi];
                }
            }
        }
        __syncthreads();
        if (grp == 0) {
#pragma unroll
            for (int qi = 0; qi < 2; qi++) {
                int rowl = wl * 32 + qi * 16 + lr;
                float m1 = mM[rowl * 2], l1 = mM[rowl * 2 + 1];
                float M  = fmaxf(m_st[qi], m1);
                float a0 = exp2f(m_st[qi] - M);
                float a1 = exp2f(m1 - M);
                float li = 1.0f / (l_st[qi] * a0 + l1 * a1);
                u16* obase = ob + (size_t)(b * SEQ + qt * 128 + wl * 32 + qi * 16) * 2048 + h * 128;
#pragma unroll
                for (int r = 0; r < 4; r++) {
                    float a0b = __shfl(a0, quad * 4 + r, 16);
                    float a1b = __shfl(a1, quad * 4 + r, 16);
                    float lib = __shfl(li, quad * 4 + r, 16);
                    int row = wl * 32 + qi * 16 + quad * 4 + r;
#pragma unroll
                    for (int nd = 0; nd < 8; nd++) {
                        float val = (o[qi][nd][r] * a0b + mO[row * 132 + nd * 16 + lr] * a1b) * lib;
                        obase[(quad * 4 + r) * 2048 + nd * 16 + lr] = f2bf(val);
                    }
                }
            }
        }
        __syncthreads();   // merge reads done before next phase restages K/V regions
    }
}

extern "C" void kernel_launch(void* const* d_in, const int* in_sizes, int n_in,
                              void* d_out, int out_size, void* d_ws, size_t ws_size,
                              hipStream_t stream) {
    (void)in_sizes; (void)n_in; (void)out_size; (void)ws_size;
    const float* x    = (const float*)d_in[0];
    const float* cosp = (const float*)d_in[1];
    const float* sinp = (const float*)d_in[2];
    const float* wq   = (const float*)d_in[3];
    const float* wk   = (const float*)d_in[4];
    const float* wv   = (const float*)d_in[5];
    const float* wo   = (const float*)d_in[6];
    float* out = (float*)d_out;

    char* ws = (char*)d_ws;
    u16* xb    = (u16*)(ws);                               // 16 MB (reused as ob)
    u16* qkvb  = (u16*)(ws + (size_t)16 * 1024 * 1024);    // 24 MB
    u16* wqkvT = (u16*)(ws + (size_t)40 * 1024 * 1024);    // 12 MB
    u16* woT   = (u16*)(ws + (size_t)52 * 1024 * 1024);    //  8 MB
    u16* vtb   = (u16*)(ws + (size_t)60 * 1024 * 1024);    //  4 MB
    u16* ob    = xb;                                       // alias: xb dead after QKV GEMM

    convert_bf16<<<8192, 256, 0, stream>>>(x, xb);
    tconv_all<<<dim3(80, 32), 256, 0, stream>>>(wq, wk, wv, wo, wqkvT, woT);
    gemm128<2><<<dim3(24, 32), 256, 0, stream>>>(xb, wqkvT, (void*)qkvb, vtb, cosp, sinp,
                                                 4096, 3072, 2048);
    flash_attn<<<256, 512, 0, stream>>>(qkvb, vtb, ob);
    gemm128<1><<<dim3(16, 32), 256, 0, stream>>>(ob, woT, (void*)out, nullptr, nullptr, nullptr,
                                                 4096, 2048, 2048);
}